// Round 1
// baseline (657.579 us; speedup 1.0000x reference)
//
#include <hip/hip_runtime.h>
#include <hip/hip_bf16.h>
#include <stdint.h>

// Problem constants (fixed by the reference)
#define NUM_RANKS 8
#define M_DIM 8192   // global token dim
#define N_DIM 4096   // output features
#define K_LOC 512    // per-rank K shard
#define K_DIM 4096   // NUM_RANKS * K_LOC — the effective GEMM K

typedef __bf16 bf16x8 __attribute__((ext_vector_type(8)));
typedef float f32x4 __attribute__((ext_vector_type(4)));

// RNE float->bf16 (bit trick; inputs are finite gaussians, no NaN handling needed)
__device__ __forceinline__ uint32_t f2bf(float f) {
    union { float f; uint32_t u; } cv;
    cv.f = f;
    uint32_t x = cv.u;
    return ((x + 0x7fffu + ((x >> 16) & 1u)) >> 16) & 0xffffu;
}

// Convert + relayout: in[src][row][k] fp32 -> out[row][src*512+k] bf16
// rowShift = log2(rows). 8 elements per thread (float4 x2 in, uint4 out).
__global__ __launch_bounds__(256) void cvt_relayout(
    const float* __restrict__ in, unsigned short* __restrict__ out, int rowShift)
{
    const long tid = (long)blockIdx.x * 256 + threadIdx.x;
    const long e = tid << 3;
    const int src = (int)(e >> (rowShift + 9));
    const int row = (int)((e >> 9) & ((1u << rowShift) - 1u));
    const int k   = (int)(e & 511);
    const float4 f0 = *(const float4*)(in + e);
    const float4 f1 = *(const float4*)(in + e + 4);
    uint4 v;
    v.x = f2bf(f0.x) | (f2bf(f0.y) << 16);
    v.y = f2bf(f0.z) | (f2bf(f0.w) << 16);
    v.z = f2bf(f1.x) | (f2bf(f1.y) << 16);
    v.w = f2bf(f1.z) | (f2bf(f1.w) << 16);
    *(uint4*)(out + ((long)row << 12) + (src << 9) + k) = v;
}

// 16B direct global->LDS (DMA, no VGPR round-trip). LDS dst semantics:
// wave-uniform base + lane*16 — our layout is arranged to match exactly.
__device__ __forceinline__ void load_lds16(const void* g, void* l) {
    __builtin_amdgcn_global_load_lds(
        (__attribute__((address_space(1))) void*)g,
        (__attribute__((address_space(3))) void*)l,
        16, 0, 0);
}

// C[M][N] = A[M][K] * B[N][K]^T, bf16 inputs, fp32 out.
// 128x128 tile, BK=32, 256 threads (4 waves), each wave does a 64x64 subtile
// as 4x4 grid of v_mfma_f32_16x16x32_bf16. m97 structure (~900 TF class).
__global__ __launch_bounds__(256) void gemm_bt(
    const unsigned short* __restrict__ A,
    const unsigned short* __restrict__ B,
    float* __restrict__ C)
{
    __shared__ unsigned short sA[128 * 32];  // 8 KiB, row-major [128][32], NO padding
    __shared__ unsigned short sB[128 * 32];  // (global_load_lds requires contiguity)

    const int t    = threadIdx.x;
    const int lane = t & 63;
    const int w    = t >> 6;
    const int wm   = w >> 1;        // wave row (0..1)
    const int wn   = w & 1;         // wave col (0..1)
    const int l16  = lane & 15;
    const int quad = lane >> 4;

    const int m0 = blockIdx.y * 128;
    const int n0 = blockIdx.x * 128;

    // Staging map: flat LDS bytes t*16 (+4096 pass2) == row=(pass*64 + t/4), col=(t&3)*8
    const int ra = t >> 2;          // 0..63
    const int ca = (t & 3) << 3;    // 0,8,16,24
    const unsigned short* gA0 = A + (long)(m0 + ra) * K_DIM + ca;
    const unsigned short* gA1 = A + (long)(m0 + 64 + ra) * K_DIM + ca;
    const unsigned short* gB0 = B + (long)(n0 + ra) * K_DIM + ca;
    const unsigned short* gB1 = B + (long)(n0 + 64 + ra) * K_DIM + ca;
    unsigned short* lA0 = sA + t * 8;
    unsigned short* lA1 = sA + 2048 + t * 8;
    unsigned short* lB0 = sB + t * 8;
    unsigned short* lB1 = sB + 2048 + t * 8;

    // Fragment element offsets: A[m=lane&15][k=quad*8+j], same for B (B^T storage)
    int aoff[4], boff[4];
#pragma unroll
    for (int i = 0; i < 4; ++i) {
        aoff[i] = (wm * 64 + i * 16 + l16) * 32 + quad * 8;
        boff[i] = (wn * 64 + i * 16 + l16) * 32 + quad * 8;
    }

    f32x4 acc[4][4];
#pragma unroll
    for (int i = 0; i < 4; ++i)
#pragma unroll
        for (int j = 0; j < 4; ++j)
            acc[i][j] = (f32x4){0.f, 0.f, 0.f, 0.f};

    for (int kt = 0; kt < K_DIM; kt += 32) {
        __syncthreads();                      // previous tile fully consumed
        load_lds16(gA0 + kt, lA0);
        load_lds16(gA1 + kt, lA1);
        load_lds16(gB0 + kt, lB0);
        load_lds16(gB1 + kt, lB1);
        __syncthreads();                      // compiler drains vmcnt before barrier

        bf16x8 af[4], bfr[4];
#pragma unroll
        for (int i = 0; i < 4; ++i) af[i]  = *(const bf16x8*)(sA + aoff[i]);
#pragma unroll
        for (int i = 0; i < 4; ++i) bfr[i] = *(const bf16x8*)(sB + boff[i]);
#pragma unroll
        for (int mi = 0; mi < 4; ++mi)
#pragma unroll
            for (int ni = 0; ni < 4; ++ni)
                acc[mi][ni] = __builtin_amdgcn_mfma_f32_16x16x32_bf16(
                    af[mi], bfr[ni], acc[mi][ni], 0, 0, 0);
    }

    // Epilogue: C/D layout col=lane&15, row=quad*4+reg (m89/m91-verified)
#pragma unroll
    for (int mi = 0; mi < 4; ++mi) {
#pragma unroll
        for (int ni = 0; ni < 4; ++ni) {
            const int col = n0 + wn * 64 + ni * 16 + l16;
#pragma unroll
            for (int r = 0; r < 4; ++r) {
                const int row = m0 + wm * 64 + mi * 16 + quad * 4 + r;
                C[(long)row * N_DIM + col] = acc[mi][ni][r];
            }
        }
    }
}

extern "C" void kernel_launch(void* const* d_in, const int* in_sizes, int n_in,
                              void* d_out, int out_size, void* d_ws, size_t ws_size,
                              hipStream_t stream)
{
    const float* a = (const float*)d_in[0];   // [8][8192][512] fp32
    const float* b = (const float*)d_in[1];   // [8][4096][512] fp32
    float* out = (float*)d_out;               // [8][1024][4096] fp32 == C[8192][4096]

    // Workspace layout: A_bf16 [8192][4096] (64 MiB) then B_bf16 [4096][4096] (32 MiB)
    unsigned short* Abf = (unsigned short*)d_ws;
    unsigned short* Bbf = Abf + (size_t)M_DIM * K_DIM;

    // a: 33.55M elems / 8 per thread / 256 = 16384 blocks; rows=8192 -> shift 13
    cvt_relayout<<<(NUM_RANKS * M_DIM * (K_LOC / 8)) / 256, 256, 0, stream>>>(a, Abf, 13);
    // b: 16.78M elems -> 8192 blocks; rows=4096 -> shift 12
    cvt_relayout<<<(NUM_RANKS * N_DIM * (K_LOC / 8)) / 256, 256, 0, stream>>>(b, Bbf, 12);

    dim3 grid(N_DIM / 128, M_DIM / 128);      // 32 x 64 = 2048 blocks
    gemm_bt<<<grid, 256, 0, stream>>>(Abf, Bbf, out);
}

// Round 2
// 647.835 us; speedup vs baseline: 1.0150x; 1.0150x over previous
//
#include <hip/hip_runtime.h>
#include <hip/hip_bf16.h>
#include <stdint.h>

// Problem constants (fixed by the reference)
#define NUM_RANKS 8
#define M_DIM 8192   // global token dim
#define N_DIM 4096   // output features
#define K_LOC 512    // per-rank K shard
#define K_DIM 4096   // NUM_RANKS * K_LOC — the effective GEMM K

typedef __bf16 bf16x8 __attribute__((ext_vector_type(8)));
typedef float f32x4 __attribute__((ext_vector_type(4)));

// RNE float->bf16 (bit trick; inputs are finite gaussians, no NaN handling needed)
__device__ __forceinline__ uint32_t f2bf(float f) {
    union { float f; uint32_t u; } cv;
    cv.f = f;
    uint32_t x = cv.u;
    return ((x + 0x7fffu + ((x >> 16) & 1u)) >> 16) & 0xffffu;
}

// Convert + relayout: in[src][row][k] fp32 -> out[row][src*512+k] bf16
// rowShift = log2(rows). 8 elements per thread (float4 x2 in, uint4 out).
__global__ __launch_bounds__(256) void cvt_relayout(
    const float* __restrict__ in, unsigned short* __restrict__ out, int rowShift)
{
    const long tid = (long)blockIdx.x * 256 + threadIdx.x;
    const long e = tid << 3;
    const int src = (int)(e >> (rowShift + 9));
    const int row = (int)((e >> 9) & ((1u << rowShift) - 1u));
    const int k   = (int)(e & 511);
    const float4 f0 = *(const float4*)(in + e);
    const float4 f1 = *(const float4*)(in + e + 4);
    uint4 v;
    v.x = f2bf(f0.x) | (f2bf(f0.y) << 16);
    v.y = f2bf(f0.z) | (f2bf(f0.w) << 16);
    v.z = f2bf(f1.x) | (f2bf(f1.y) << 16);
    v.w = f2bf(f1.z) | (f2bf(f1.w) << 16);
    *(uint4*)(out + ((long)row << 12) + (src << 9) + k) = v;
}

// 16B direct global->LDS (DMA, no VGPR round-trip). LDS dst semantics:
// wave-uniform base + lane*16 — layout arranged to match exactly.
__device__ __forceinline__ void load_lds16(const void* g, void* l) {
    __builtin_amdgcn_global_load_lds(
        (__attribute__((address_space(1))) void*)g,
        (__attribute__((address_space(3))) void*)l,
        16, 0, 0);
}

// C[M][N] = A[M][K] * B[N][K]^T, bf16 inputs, fp32 out.
// 128x128 tile, BK=32, 256 threads (4 waves), each wave 64x64 subtile as
// 4x4 v_mfma_f32_16x16x32_bf16.
//
// LDS XOR swizzle (R1): row m's logical 16B chunk q lives at slot
// q ^ ((m>>1)&3). Readers at row m=base+l16, quad q hit start words
// 16*(m&1) + 4*(q^((m>>1)&3)) — full 32-bank spread, 2-way max (free per
// m136), vs 8-way in the unswizzled layout (3.35e7 conflicts measured R1).
__global__ __launch_bounds__(256) void gemm_bt(
    const unsigned short* __restrict__ A,
    const unsigned short* __restrict__ B,
    float* __restrict__ C)
{
    __shared__ unsigned short sA[128 * 32];  // 8 KiB, [128 rows][4 chunks of 8 bf16]
    __shared__ unsigned short sB[128 * 32];

    const int t    = threadIdx.x;
    const int lane = t & 63;
    const int w    = t >> 6;
    const int wm   = w >> 1;        // wave row (0..1)
    const int wn   = w & 1;         // wave col (0..1)
    const int l16  = lane & 15;
    const int quad = lane >> 4;

    const int m0 = blockIdx.y * 128;
    const int n0 = blockIdx.x * 128;

    // Staging map: thread t -> LDS bytes t*16 (+4096 pass2) = row (pass*64+t/4),
    // slot (t&3). Swizzle: fetch global chunk (t&3) ^ ((t>>3)&3).
    // (+64 rows doesn't change (row>>1)&3, so same ca serves both passes.)
    const int ra = t >> 2;                       // 0..63
    const int ca = (((t & 3) ^ ((t >> 3) & 3)) << 3);  // global k-offset in elems
    const unsigned short* gA0 = A + (long)(m0 + ra) * K_DIM + ca;
    const unsigned short* gA1 = A + (long)(m0 + 64 + ra) * K_DIM + ca;
    const unsigned short* gB0 = B + (long)(n0 + ra) * K_DIM + ca;
    const unsigned short* gB1 = B + (long)(n0 + 64 + ra) * K_DIM + ca;
    unsigned short* lA0 = sA + t * 8;
    unsigned short* lA1 = sA + 2048 + t * 8;
    unsigned short* lB0 = sB + t * 8;
    unsigned short* lB1 = sB + 2048 + t * 8;

    // Fragment offsets: row m = w?*64 + i*16 + l16, logical chunk = quad.
    // Swizzled slot = quad ^ ((m>>1)&3) = quad ^ ((l16>>1)&3).
    const int csw = (quad ^ ((l16 >> 1) & 3)) << 3;  // elems
    int aoff[4], boff[4];
#pragma unroll
    for (int i = 0; i < 4; ++i) {
        aoff[i] = (wm * 64 + i * 16 + l16) * 32 + csw;
        boff[i] = (wn * 64 + i * 16 + l16) * 32 + csw;
    }

    f32x4 acc[4][4];
#pragma unroll
    for (int i = 0; i < 4; ++i)
#pragma unroll
        for (int j = 0; j < 4; ++j)
            acc[i][j] = (f32x4){0.f, 0.f, 0.f, 0.f};

    for (int kt = 0; kt < K_DIM; kt += 32) {
        __syncthreads();                      // previous tile fully consumed
        load_lds16(gA0 + kt, lA0);
        load_lds16(gA1 + kt, lA1);
        load_lds16(gB0 + kt, lB0);
        load_lds16(gB1 + kt, lB1);
        __syncthreads();                      // drains vmcnt before barrier

        bf16x8 af[4], bfr[4];
#pragma unroll
        for (int i = 0; i < 4; ++i) af[i]  = *(const bf16x8*)(sA + aoff[i]);
#pragma unroll
        for (int i = 0; i < 4; ++i) bfr[i] = *(const bf16x8*)(sB + boff[i]);
#pragma unroll
        for (int mi = 0; mi < 4; ++mi)
#pragma unroll
            for (int ni = 0; ni < 4; ++ni)
                acc[mi][ni] = __builtin_amdgcn_mfma_f32_16x16x32_bf16(
                    af[mi], bfr[ni], acc[mi][ni], 0, 0, 0);
    }

    // Epilogue: C/D layout col=lane&15, row=quad*4+reg (m89/m91-verified)
#pragma unroll
    for (int mi = 0; mi < 4; ++mi) {
#pragma unroll
        for (int ni = 0; ni < 4; ++ni) {
            const int col = n0 + wn * 64 + ni * 16 + l16;
#pragma unroll
            for (int r = 0; r < 4; ++r) {
                const int row = m0 + wm * 64 + mi * 16 + quad * 4 + r;
                C[(long)row * N_DIM + col] = acc[mi][ni][r];
            }
        }
    }
}

extern "C" void kernel_launch(void* const* d_in, const int* in_sizes, int n_in,
                              void* d_out, int out_size, void* d_ws, size_t ws_size,
                              hipStream_t stream)
{
    const float* a = (const float*)d_in[0];   // [8][8192][512] fp32
    const float* b = (const float*)d_in[1];   // [8][4096][512] fp32
    float* out = (float*)d_out;               // [8][1024][4096] fp32 == C[8192][4096]

    // Workspace layout: A_bf16 [8192][4096] (64 MiB) then B_bf16 [4096][4096] (32 MiB)
    unsigned short* Abf = (unsigned short*)d_ws;
    unsigned short* Bbf = Abf + (size_t)M_DIM * K_DIM;

    cvt_relayout<<<(NUM_RANKS * M_DIM * (K_LOC / 8)) / 256, 256, 0, stream>>>(a, Abf, 13);
    cvt_relayout<<<(NUM_RANKS * N_DIM * (K_LOC / 8)) / 256, 256, 0, stream>>>(b, Bbf, 12);

    dim3 grid(N_DIM / 128, M_DIM / 128);      // 32 x 64 = 2048 blocks
    gemm_bt<<<grid, 256, 0, stream>>>(Abf, Bbf, out);
}